// Round 22
// baseline (712.395 us; speedup 1.0000x reference)
//
#include <hip/hip_runtime.h>
#include <stdint.h>

#define D 4096
#define CAP 2560          // compacted-dim capacity (counts ~2048 +- ~45)
#define CTK 80            // CAP/32 k-tile stride

typedef __attribute__((ext_vector_type(8))) short bf16x8;
typedef __attribute__((ext_vector_type(4))) float f32x4;

#define MFMA16 __builtin_amdgcn_mfma_f32_16x16x32_bf16

__device__ __forceinline__ float sgnf(float z) {
    return (z > 0.f) ? 1.f : ((z < 0.f) ? -1.f : 0.f);
}
__device__ __forceinline__ uint cvtpk(float a, float b) {
    uint r;
    asm("v_cvt_pk_bf16_f32 %0, %1, %2" : "=v"(r) : "v"(a), "v"(b));
    return r;
}
__device__ __forceinline__ void split3_pk(float f0, float f1, uint& hp, uint& mp, uint& lp) {
    hp = cvtpk(f0, f1);
    float h0 = __uint_as_float(hp << 16);
    float h1 = __uint_as_float(hp & 0xffff0000u);
    float r0 = f0 - h0, r1 = f1 - h1;
    mp = cvtpk(r0, r1);
    float m0 = __uint_as_float(mp << 16);
    float m1 = __uint_as_float(mp & 0xffff0000u);
    lp = cvtpk(r0 - m0, r1 - m1);
}

// ---- forward GEMV: bit-exact numpy-f32 emulation (R19-proven, pipelined) ----
__global__ __launch_bounds__(256) void gemv_blas8(const float* __restrict__ W,
                                                  const float* __restrict__ v,
                                                  const float* __restrict__ bias,
                                                  float* __restrict__ z,
                                                  float* __restrict__ act, int doAct) {
    __shared__ float vs[D];
    {
        const float4* v4 = (const float4*)v;
        float4* s4 = (float4*)vs;
#pragma unroll
        for (int q = 0; q < 4; q++) s4[threadIdx.x + q * 256] = v4[threadIdx.x + q * 256];
    }
    __syncthreads();
    int gid = blockIdx.x * 256 + threadIdx.x;
    int row = gid >> 3;
    int l = gid & 7;
    const float* wr = W + (size_t)row * D + l;
    float wb0[16], wb1[16], wb2[16];
    float acc = 0.f;
#pragma unroll
    for (int u = 0; u < 16; u++) wb0[u] = wr[u * 8];
#pragma unroll
    for (int u = 0; u < 16; u++) wb1[u] = wr[(16 + u) * 8];
#pragma unroll
    for (int c = 0; c < 32; c++) {
        if (c + 2 < 32) {
            float* dst = ((c + 2) % 3 == 0) ? wb0 : ((c + 2) % 3 == 1) ? wb1 : wb2;
#pragma unroll
            for (int u = 0; u < 16; u++) dst[u] = wr[((c + 2) * 16 + u) * 8];
        }
        const float* cur = (c % 3 == 0) ? wb0 : (c % 3 == 1) ? wb1 : wb2;
#pragma unroll
        for (int u = 0; u < 16; u++) acc = fmaf(cur[u], vs[l + (c * 16 + u) * 8], acc);
    }
    float b = acc + __shfl_xor(acc, 4);
    float c2 = b + __shfl_xor(b, 1);
    float s = c2 + __shfl_xor(c2, 2);
    if (l == 0) {
        z[row] = s;
        if (doAct) act[row] = fmaxf(s + bias[row], 0.f);
    }
}

__global__ __launch_bounds__(256) void vecprep32(const float* __restrict__ z1,
                                                 const float* __restrict__ z2,
                                                 const float* __restrict__ z3,
                                                 const float* __restrict__ a1,
                                                 const float* __restrict__ a2,
                                                 const float* __restrict__ b3,
                                                 float* __restrict__ out,
                                                 float* __restrict__ s3,
                                                 float* __restrict__ g2,
                                                 float* __restrict__ g1) {
    int i = blockIdx.x * 256 + threadIdx.x;
    float z3v = z3[i];
    float o = z3v + b3[i];
    out[i] = o;
    s3[i] = o / (z3v + 1e-9f * sgnf(z3v));
    float z2v = z2[i];
    g2[i] = a2[i] / (z2v + 1e-9f * sgnf(z2v));
    float z1v = z1[i];
    g1[i] = a1[i] / (z1v + 1e-9f * sgnf(z1v));
}

// ---- compaction scan (1 wave, deterministic) ----
__global__ __launch_bounds__(64) void scan2(const float* __restrict__ g2,
                                            const float* __restrict__ g1,
                                            int* __restrict__ idx2, float* __restrict__ g2c,
                                            int* __restrict__ idx1, float* __restrict__ g1c,
                                            int* __restrict__ cnt) {
    int lane = threadIdx.x;
    unsigned long long lt = (lane == 63) ? 0x7fffffffffffffffULL : ((1ULL << lane) - 1ULL);
    int base = 0;
    for (int c = 0; c < 64; ++c) {
        float v = g2[c * 64 + lane];
        bool nz = (v != 0.f);
        unsigned long long mask = __ballot(nz);
        int pre = __popcll(mask & lt);
        if (nz && base + pre < CAP) { idx2[base + pre] = c * 64 + lane; g2c[base + pre] = v; }
        base += __popcll(mask);
    }
    if (base > CAP) base = CAP;
    for (int i = base + lane; i < CAP; i += 64) { idx2[i] = 0; g2c[i] = 0.f; }
    int K2pad = (base + 127) & ~127;
    int b1 = 0;
    for (int c = 0; c < 64; ++c) {
        float v = g1[c * 64 + lane];
        bool nz = (v != 0.f);
        unsigned long long mask = __ballot(nz);
        int pre = __popcll(mask & lt);
        if (nz && b1 + pre < CAP) { idx1[b1 + pre] = c * 64 + lane; g1c[b1 + pre] = v; }
        b1 += __popcll(mask);
    }
    if (b1 > CAP) b1 = CAP;
    for (int i = b1 + lane; i < CAP; i += 64) { idx1[i] = 0; g1c[i] = 0.f; }
    int N1pad = (b1 + 127) & ~127;
    if (lane == 0) {
        cnt[0] = K2pad / 32;
        cnt[1] = N1pad / 32;
        cnt[2] = N1pad;
        cnt[3] = K2pad;
    }
}

// ---- A1 planes: val = s3[i]*W3[i,idx2[kc]]*g2c[kc] (256-row-block layout) ----
__global__ __launch_bounds__(256) void prepA1c(const float* __restrict__ W3,
                                               const float* __restrict__ s3,
                                               const int* __restrict__ idx2,
                                               const float* __restrict__ g2c,
                                               ushort* __restrict__ Ph,
                                               ushort* __restrict__ Pm,
                                               ushort* __restrict__ Pl) {
    size_t ci = (size_t)blockIdx.x * 256 + threadIdx.x;
    int cell = (int)(ci & 1023);
    int kt = (int)((ci >> 10) % CTK);
    int bi2 = (int)(ci / (1024 * CTK));
    int mm = cell >> 6, gg = (cell >> 4) & 3, ri = cell & 15;
    int i = bi2 * 256 + mm * 16 + ri;
    int kc0 = kt * 32 + gg * 8;
    float s = s3[i];
    const float* w3r = W3 + (size_t)i * D;
    float v[8];
#pragma unroll
    for (int j = 0; j < 8; j++) v[j] = w3r[idx2[kc0 + j]] * (s * g2c[kc0 + j]);
    uint hp[4], mp[4], lp[4];
#pragma unroll
    for (int j = 0; j < 4; j++) split3_pk(v[2 * j], v[2 * j + 1], hp[j], mp[j], lp[j]);
    size_t dst = ci * 8;
    uint4 u;
    u.x = hp[0]; u.y = hp[1]; u.z = hp[2]; u.w = hp[3]; *(uint4*)(Ph + dst) = u;
    u.x = mp[0]; u.y = mp[1]; u.z = mp[2]; u.w = mp[3]; *(uint4*)(Pm + dst) = u;
    u.x = lp[0]; u.y = lp[1]; u.z = lp[2]; u.w = lp[3]; *(uint4*)(Pl + dst) = u;
}

// ---- B1 planes: val = W2[idx2[kc], idx1[colc]] (double-gather) ----
__global__ __launch_bounds__(256) void prepB1c(const float* __restrict__ W2,
                                               const int* __restrict__ idx2,
                                               const int* __restrict__ idx1,
                                               ushort* __restrict__ Ph,
                                               ushort* __restrict__ Pm,
                                               ushort* __restrict__ Pl) {
    size_t ci = (size_t)blockIdx.x * 256 + threadIdx.x;
    int cell = (int)(ci & 511);
    int kt = (int)((ci >> 9) % CTK);
    int bi = (int)(ci / (512 * CTK));
    int m = cell >> 6, g = (cell >> 4) & 3, r = cell & 15;
    int col = idx1[bi * 128 + m * 16 + r];
    int kc0 = kt * 32 + g * 8;
    float v[8];
#pragma unroll
    for (int j = 0; j < 8; j++) v[j] = W2[(size_t)idx2[kc0 + j] * D + col];
    uint hp[4], mp[4], lp[4];
#pragma unroll
    for (int j = 0; j < 4; j++) split3_pk(v[2 * j], v[2 * j + 1], hp[j], mp[j], lp[j]);
    size_t dst = ci * 8;
    uint4 u;
    u.x = hp[0]; u.y = hp[1]; u.z = hp[2]; u.w = hp[3]; *(uint4*)(Ph + dst) = u;
    u.x = mp[0]; u.y = mp[1]; u.z = mp[2]; u.w = mp[3]; *(uint4*)(Pm + dst) = u;
    u.x = lp[0]; u.y = lp[1]; u.z = lp[2]; u.w = lp[3]; *(uint4*)(Pl + dst) = u;
}

// ---- B2 planes: val = W1[idx1[kc], col] (row-gather, LDS-tiled) ----
__global__ __launch_bounds__(256) void prepB2c(const float* __restrict__ W1,
                                               const int* __restrict__ idx1,
                                               ushort* __restrict__ Ph,
                                               ushort* __restrict__ Pm,
                                               ushort* __restrict__ Pl) {
    __shared__ float tile[64][129];
    int bi = blockIdx.x / (CAP / 64);
    int kch = blockIdx.x % (CAP / 64);
    int k0 = kch * 64;
    int c0 = bi * 128;
    int t = threadIdx.x;
#pragma unroll
    for (int q = 0; q < 8; q++) {
        int idx = t + q * 256;
        int rr = idx >> 5;
        int c4 = idx & 31;
        int row = idx1[k0 + rr];
        float4 wv = *(const float4*)(W1 + (size_t)row * D + c0 + c4 * 4);
        tile[rr][c4 * 4 + 0] = wv.x;
        tile[rr][c4 * 4 + 1] = wv.y;
        tile[rr][c4 * 4 + 2] = wv.z;
        tile[rr][c4 * 4 + 3] = wv.w;
    }
    __syncthreads();
#pragma unroll
    for (int q = 0; q < 4; q++) {
        int oi = t + q * 256;
        int ktl = oi >> 9;
        int rem = oi & 511;
        int m = rem >> 6, g = (rem >> 4) & 3, r = rem & 15;
        int col = m * 16 + r;
        float vv[8];
#pragma unroll
        for (int j = 0; j < 8; j++) vv[j] = tile[ktl * 32 + g * 8 + j][col];
        uint hp[4], mp[4], lp[4];
#pragma unroll
        for (int j = 0; j < 4; j++) split3_pk(vv[2 * j], vv[2 * j + 1], hp[j], mp[j], lp[j]);
        size_t dst = (((size_t)bi * CTK + kch * 2 + ktl) * 512 + rem) * 8;
        uint4 u;
        u.x = hp[0]; u.y = hp[1]; u.z = hp[2]; u.w = hp[3]; *(uint4*)(Ph + dst) = u;
        u.x = mp[0]; u.y = mp[1]; u.z = mp[2]; u.w = mp[3]; *(uint4*)(Pm + dst) = u;
        u.x = lp[0]; u.y = lp[1]; u.z = lp[2]; u.w = lp[3]; *(uint4*)(Pl + dst) = u;
    }
}

// ---- gemm_c2: 256x128 tile, 512 threads (8 waves, 4M x 2N), all-DMA,
// A+B single-buffered (72 KB) -> 2 blocks/CU -> 4 waves/SIMD. Per-product
// fragment loading caps live frag VGPRs at 32 (fits 128-reg budget).
template <int MODE>
__global__ __launch_bounds__(512, 4) void gemm_c2(const ushort* __restrict__ Ah,
                                                  const ushort* __restrict__ Am_,
                                                  const ushort* __restrict__ Al_,
                                                  const ushort* __restrict__ Bh,
                                                  const ushort* __restrict__ Bm_,
                                                  const ushort* __restrict__ Bl_,
                                                  const float* __restrict__ cs,
                                                  const int* __restrict__ cnt,
                                                  float* __restrict__ O,
                                                  ushort* __restrict__ Cph,
                                                  ushort* __restrict__ Cpm,
                                                  ushort* __restrict__ Cpl_) {
    const int NT = cnt[MODE == 1 ? 0 : 1];
    if (MODE == 1 && (int)blockIdx.x * 128 >= cnt[2]) return;
    __shared__ ushort ldsA[3][8192];  // 48 KB (256 rows x 32 k), single
    __shared__ ushort ldsB[3][4096];  // 24 KB, single
    int t = threadIdx.x;
    int lane = t & 63, wv = t >> 6;
    int wm = wv >> 1, wn = wv & 1;
    int r = lane & 15, g = lane >> 4;
    int bx = blockIdx.x, by = blockIdx.y;
    size_t row0 = (size_t)by * 256, col0 = (size_t)bx * 128;

    f32x4 acc[4][4];
#pragma unroll
    for (int m = 0; m < 4; m++)
#pragma unroll
        for (int n = 0; n < 4; n++) acc[m][n] = (f32x4){0.f, 0.f, 0.f, 0.f};

    size_t abase = (size_t)by * CTK * 8192;  // 256-row-block plane layout

    auto DMAA = [&](int kt) {
        size_t at = abase + (size_t)kt * 8192;
        const ushort* asrc[3] = {Ah + at, Am_ + at, Al_ + at};
#pragma unroll
        for (int p = 0; p < 3; p++) {
            __builtin_amdgcn_global_load_lds(
                (const __attribute__((address_space(1))) uint32_t*)(asrc[p] + (size_t)t * 8),
                (__attribute__((address_space(3))) uint32_t*)(&ldsA[p][t * 8]), 16, 0, 0);
            __builtin_amdgcn_global_load_lds(
                (const __attribute__((address_space(1))) uint32_t*)(asrc[p] + (size_t)(t + 512) * 8),
                (__attribute__((address_space(3))) uint32_t*)(&ldsA[p][(t + 512) * 8]), 16, 0, 0);
        }
    };
    auto DMAB = [&](int kt) {
        size_t bt = ((size_t)bx * CTK + kt) * 4096;
        const ushort* bsrc[3] = {Bh + bt, Bm_ + bt, Bl_ + bt};
#pragma unroll
        for (int p = 0; p < 3; p++) {
            __builtin_amdgcn_global_load_lds(
                (const __attribute__((address_space(1))) uint32_t*)(bsrc[p] + (size_t)t * 8),
                (__attribute__((address_space(3))) uint32_t*)(&ldsB[p][t * 8]), 16, 0, 0);
        }
    };

    // per-product fragment loads: b-plane held across the a-plane sweep
    auto PROD = [&](int pa, int pb) {
        bf16x8 a[4], b[4];
#pragma unroll
        for (int n = 0; n < 4; n++)
            b[n] = *(const bf16x8*)&ldsB[pb][((wn * 4 + n) * 64 + lane) * 8];
#pragma unroll
        for (int m = 0; m < 4; m++)
            a[m] = *(const bf16x8*)&ldsA[pa][((wm * 4 + m) * 64 + lane) * 8];
#pragma unroll
        for (int m = 0; m < 4; m++)
#pragma unroll
            for (int n = 0; n < 4; n++)
                acc[m][n] = MFMA16(a[m], b[n], acc[m][n], 0, 0, 0);
    };

    auto MFMA_PHASE = [&]() {
        __builtin_amdgcn_s_setprio(1);
        PROD(0, 0);  // hh
        PROD(0, 1);  // hm
        PROD(1, 0);  // mh
        PROD(1, 1);  // mm
        PROD(0, 2);  // hl
        PROD(2, 0);  // lh
        __builtin_amdgcn_s_setprio(0);
    };

    DMAA(0);
    DMAB(0);
    asm volatile("s_waitcnt vmcnt(0)" ::: "memory");
    __builtin_amdgcn_sched_barrier(0);
    __builtin_amdgcn_s_barrier();
    __builtin_amdgcn_sched_barrier(0);

    for (int tt = 0; tt < NT; ++tt) {
        MFMA_PHASE();
        __builtin_amdgcn_sched_barrier(0);
        __builtin_amdgcn_s_barrier();  // all waves done reading ldsA/ldsB
        __builtin_amdgcn_sched_barrier(0);
        if (tt < NT - 1) {
            DMAA(tt + 1);
            DMAB(tt + 1);
            asm volatile("s_waitcnt vmcnt(0)" ::: "memory");
            __builtin_amdgcn_sched_barrier(0);
            __builtin_amdgcn_s_barrier();
            __builtin_amdgcn_sched_barrier(0);
        }
    }

    float csv[4];
#pragma unroll
    for (int n = 0; n < 4; n++) csv[n] = cs[col0 + wn * 64 + n * 16 + r];
#pragma unroll
    for (int m = 0; m < 4; m++)
#pragma unroll
        for (int n = 0; n < 4; n++) {
            if (MODE == 0) {
#pragma unroll
                for (int j = 0; j < 4; j++) {
                    size_t grow = row0 + wm * 64 + m * 16 + g * 4 + j;
                    size_t gcol = col0 + wn * 64 + n * 16 + r;
                    O[grow * D + gcol] = acc[m][n][j] * csv[n];
                }
            } else {
                float v0 = acc[m][n][0] * csv[n], v1 = acc[m][n][1] * csv[n];
                float v2 = acc[m][n][2] * csv[n], v3 = acc[m][n][3] * csv[n];
                uint hp0, mp0, lp0, hp1, mp1, lp1;
                split3_pk(v0, v1, hp0, mp0, lp0);
                split3_pk(v2, v3, hp1, mp1, lp1);
                int k = (int)(col0 + wn * 64 + n * 16 + r);  // compact col = GEMM2 k
                int ktc = k >> 5, gg = (k & 31) >> 3, jj = k & 7;
#pragma unroll
                for (int j = 0; j < 4; j++) {
                    int i = (int)(row0 + wm * 64 + m * 16 + g * 4 + j);
                    int bi = i >> 8, mm = (i & 255) >> 4, ri = i & 15;
                    size_t off = ((size_t)bi * CTK + ktc) * 8192 +
                                 (size_t)(mm * 64 + gg * 16 + ri) * 8 + jj;
                    uint hpk = (j < 2) ? hp0 : hp1;
                    uint mpk = (j < 2) ? mp0 : mp1;
                    uint lpk = (j < 2) ? lp0 : lp1;
                    int sh = (j & 1) * 16;
                    Cph[off] = (ushort)(hpk >> sh);
                    Cpm[off] = (ushort)(mpk >> sh);
                    Cpl_[off] = (ushort)(lpk >> sh);
                }
            }
        }
}

// ================= fallback tier kernels (R19-proven) =================
__global__ __launch_bounds__(256) void prepBT(const float* __restrict__ W,
                                              ushort* __restrict__ Ph,
                                              ushort* __restrict__ Pm,
                                              ushort* __restrict__ Pl) {
    __shared__ float tile[64][129];
    int bi = blockIdx.x >> 6;
    int kpair = blockIdx.x & 63;
    int k0 = kpair * 64;
    int c0 = bi * 128;
    int t = threadIdx.x;
#pragma unroll
    for (int q = 0; q < 8; q++) {
        int idx = t + q * 256;
        int rr = idx >> 5;
        int c4 = idx & 31;
        float4 wv = *(const float4*)(W + (size_t)(k0 + rr) * D + c0 + c4 * 4);
        tile[rr][c4 * 4 + 0] = wv.x;
        tile[rr][c4 * 4 + 1] = wv.y;
        tile[rr][c4 * 4 + 2] = wv.z;
        tile[rr][c4 * 4 + 3] = wv.w;
    }
    __syncthreads();
#pragma unroll
    for (int q = 0; q < 4; q++) {
        int oi = t + q * 256;
        int ktl = oi >> 9;
        int rem = oi & 511;
        int m = rem >> 6, g = (rem >> 4) & 3, r = rem & 15;
        int col = m * 16 + r;
        float vv[8];
#pragma unroll
        for (int j = 0; j < 8; j++) vv[j] = tile[ktl * 32 + g * 8 + j][col];
        uint hp[4], mp[4], lp[4];
#pragma unroll
        for (int j = 0; j < 4; j++) split3_pk(vv[2 * j], vv[2 * j + 1], hp[j], mp[j], lp[j]);
        size_t dst = (((size_t)bi * 128 + kpair * 2 + ktl) * 512 + rem) * 8;
        uint4 u;
        u.x = hp[0]; u.y = hp[1]; u.z = hp[2]; u.w = hp[3]; *(uint4*)(Ph + dst) = u;
        u.x = mp[0]; u.y = mp[1]; u.z = mp[2]; u.w = mp[3]; *(uint4*)(Pm + dst) = u;
        u.x = lp[0]; u.y = lp[1]; u.z = lp[2]; u.w = lp[3]; *(uint4*)(Pl + dst) = u;
    }
}

template <int SCALED>
__global__ __launch_bounds__(256, 2) void gemm_bs(const float* __restrict__ A,
                                                  const ushort* __restrict__ Bh,
                                                  const ushort* __restrict__ Bm_,
                                                  const ushort* __restrict__ Bl_,
                                                  const float* __restrict__ rs,
                                                  const float* __restrict__ ks,
                                                  const float* __restrict__ cs,
                                                  float* __restrict__ O) {
    __shared__ ushort ldsA[3][4096];
    __shared__ ushort ldsB[2][3][4096];
    int t = threadIdx.x;
    int lane = t & 63, wv = t >> 6;
    int wr = wv >> 1, wc = wv & 1;
    int r = lane & 15, g = lane >> 4;
    int bx = blockIdx.x, by = blockIdx.y;
    size_t row0 = (size_t)by * 128, col0 = (size_t)bx * 128;
    int rr = t >> 1;
    int kh = t & 1;
    int cellb0 = ((rr >> 4) * 64 + (kh * 2 + 0) * 16 + (rr & 15)) * 8;
    int cellb1 = ((rr >> 4) * 64 + (kh * 2 + 1) * 16 + (rr & 15)) * 8;
    f32x4 acc[4][4];
#pragma unroll
    for (int m = 0; m < 4; m++)
#pragma unroll
        for (int n = 0; n < 4; n++) acc[m][n] = (f32x4){0.f, 0.f, 0.f, 0.f};
    float rsv = SCALED ? rs[row0 + rr] : 0.f;
    const float* arow = A + (row0 + rr) * (size_t)D;
    float av[16];
    auto LOADA = [&](int k0) {
        const float4* pa = (const float4*)(arow + k0 + kh * 16);
#pragma unroll
        for (int qq = 0; qq < 4; qq++) {
            float4 w = pa[qq];
            av[qq * 4 + 0] = w.x; av[qq * 4 + 1] = w.y;
            av[qq * 4 + 2] = w.z; av[qq * 4 + 3] = w.w;
        }
        if (SCALED) {
            const float4* pk = (const float4*)(ks + k0 + kh * 16);
#pragma unroll
            for (int qq = 0; qq < 4; qq++) {
                float4 kk = pk[qq];
                av[qq * 4 + 0] *= rsv * kk.x; av[qq * 4 + 1] *= rsv * kk.y;
                av[qq * 4 + 2] *= rsv * kk.z; av[qq * 4 + 3] *= rsv * kk.w;
            }
        }
    };
    auto DMAB = [&](int kt, int buf) {
        size_t bt = ((size_t)bx * 128 + kt) * 4096;
        const ushort* bsrc[3] = {Bh + bt, Bm_ + bt, Bl_ + bt};
#pragma unroll
        for (int p = 0; p < 3; p++) {
            __builtin_amdgcn_global_load_lds(
                (const __attribute__((address_space(1))) uint32_t*)(bsrc[p] + (size_t)t * 8),
                (__attribute__((address_space(3))) uint32_t*)(&ldsB[buf][p][t * 8]), 16, 0, 0);
            __builtin_amdgcn_global_load_lds(
                (const __attribute__((address_space(1))) uint32_t*)(bsrc[p] + (size_t)(t + 256) * 8),
                (__attribute__((address_space(3))) uint32_t*)(&ldsB[buf][p][(t + 256) * 8]), 16, 0, 0);
        }
    };
    auto SPLITA = [&]() {
        uint hp[8], mp[8], lp[8];
#pragma unroll
        for (int j = 0; j < 8; j++) split3_pk(av[2 * j], av[2 * j + 1], hp[j], mp[j], lp[j]);
        uint4 u;
        u.x = hp[0]; u.y = hp[1]; u.z = hp[2]; u.w = hp[3]; *(uint4*)&ldsA[0][cellb0] = u;
        u.x = hp[4]; u.y = hp[5]; u.z = hp[6]; u.w = hp[7]; *(uint4*)&ldsA[0][cellb1] = u;
        u.x = mp[0]; u.y = mp[1]; u.z = mp[2]; u.w = mp[3]; *(uint4*)&ldsA[1][cellb0] = u;
        u.x = mp[4]; u.y = mp[5]; u.z = mp[6]; u.w = mp[7]; *(uint4*)&ldsA[1][cellb1] = u;
        u.x = lp[0]; u.y = lp[1]; u.z = lp[2]; u.w = lp[3]; *(uint4*)&ldsA[2][cellb0] = u;
        u.x = lp[4]; u.y = lp[5]; u.z = lp[6]; u.w = lp[7]; *(uint4*)&ldsA[2][cellb1] = u;
    };
    auto MFMA_PHASE = [&](int buf) {
        bf16x8 bh[4], bm[4], bl[4];
#pragma unroll
        for (int n = 0; n < 4; n++) bh[n] = *(const bf16x8*)&ldsB[buf][0][(wc * 4 + n) * 512 + lane * 8];
#pragma unroll
        for (int n = 0; n < 4; n++) bm[n] = *(const bf16x8*)&ldsB[buf][1][(wc * 4 + n) * 512 + lane * 8];
#pragma unroll
        for (int n = 0; n < 4; n++) bl[n] = *(const bf16x8*)&ldsB[buf][2][(wc * 4 + n) * 512 + lane * 8];
        {
            bf16x8 a[4];
#pragma unroll
            for (int m = 0; m < 4; m++) a[m] = *(const bf16x8*)&ldsA[0][(wr * 4 + m) * 512 + lane * 8];
#pragma unroll
            for (int m = 0; m < 4; m++)
#pragma unroll
                for (int n = 0; n < 4; n++) {
                    acc[m][n] = MFMA16(a[m], bh[n], acc[m][n], 0, 0, 0);
                    acc[m][n] = MFMA16(a[m], bm[n], acc[m][n], 0, 0, 0);
                    acc[m][n] = MFMA16(a[m], bl[n], acc[m][n], 0, 0, 0);
                }
        }
        {
            bf16x8 a[4];
#pragma unroll
            for (int m = 0; m < 4; m++) a[m] = *(const bf16x8*)&ldsA[1][(wr * 4 + m) * 512 + lane * 8];
#pragma unroll
            for (int m = 0; m < 4; m++)
#pragma unroll
                for (int n = 0; n < 4; n++) {
                    acc[m][n] = MFMA16(a[m], bh[n], acc[m][n], 0, 0, 0);
                    acc[m][n] = MFMA16(a[m], bm[n], acc[m][n], 0, 0, 0);
                }
        }
        {
            bf16x8 a[4];
#pragma unroll
            for (int m = 0; m < 4; m++) a[m] = *(const bf16x8*)&ldsA[2][(wr * 4 + m) * 512 + lane * 8];
#pragma unroll
            for (int m = 0; m < 4; m++)
#pragma unroll
                for (int n = 0; n < 4; n++)
                    acc[m][n] = MFMA16(a[m], bh[n], acc[m][n], 0, 0, 0);
        }
    };
    const int NT = D / 32;
    LOADA(0);
    SPLITA();
    DMAB(0, 0);
    LOADA(32);
    DMAB(1, 1);
    asm volatile("s_waitcnt vmcnt(6) lgkmcnt(0)" ::: "memory");
    __builtin_amdgcn_s_barrier();
    __builtin_amdgcn_sched_barrier(0);
    for (int tt = 0; tt < NT; ++tt) {
        MFMA_PHASE(tt & 1);
        __builtin_amdgcn_sched_barrier(0);
        __builtin_amdgcn_s_barrier();
        __builtin_amdgcn_sched_barrier(0);
        if (tt < NT - 1) {
            SPLITA();
            if (tt < NT - 2) {
                LOADA((tt + 2) * 32);
                DMAB(tt + 2, tt & 1);
                asm volatile("s_waitcnt vmcnt(6) lgkmcnt(0)" ::: "memory");
            } else {
                asm volatile("s_waitcnt vmcnt(0) lgkmcnt(0)" ::: "memory");
            }
            __builtin_amdgcn_s_barrier();
            __builtin_amdgcn_sched_barrier(0);
        }
    }
    float csv[4];
#pragma unroll
    for (int n = 0; n < 4; n++) csv[n] = cs[col0 + wc * 64 + n * 16 + r];
#pragma unroll
    for (int m = 0; m < 4; m++)
#pragma unroll
        for (int n = 0; n < 4; n++)
#pragma unroll
            for (int j = 0; j < 4; j++) {
                size_t grow = row0 + wr * 64 + m * 16 + g * 4 + j;
                size_t gcol = col0 + wc * 64 + n * 16 + r;
                O[grow * D + gcol] = acc[m][n][j] * csv[n];
            }
}

extern "C" void kernel_launch(void* const* d_in, const int* in_sizes, int n_in,
                              void* d_out, int out_size, void* d_ws, size_t ws_size,
                              hipStream_t stream) {
    const float* x = (const float*)d_in[0];
    const float* W1 = (const float*)d_in[1];
    const float* b1 = (const float*)d_in[2];
    const float* W2 = (const float*)d_in[3];
    const float* b2 = (const float*)d_in[4];
    const float* W3 = (const float*)d_in[5];
    const float* b3 = (const float*)d_in[6];

    float* out = (float*)d_out;
    float* Rout = out + D;

    char* ws = (char*)d_ws;
    float* z1 = (float*)ws;
    float* z2 = z1 + D;
    float* z3 = z2 + D;
    float* a1 = z3 + D;
    float* a2 = a1 + D;
    float* s3 = a2 + D;
    float* g2 = s3 + D;
    float* g1 = g2 + D;
    size_t smallB = (size_t)D * 8 * sizeof(float);

    // forward pass (bit-exact numpy-f32 emulation)
    gemv_blas8<<<(D * 8) / 256, 256, 0, stream>>>(W1, x, b1, z1, a1, 1);
    gemv_blas8<<<(D * 8) / 256, 256, 0, stream>>>(W2, a1, b2, z2, a2, 1);
    gemv_blas8<<<(D * 8) / 256, 256, 0, stream>>>(W3, a2, b3, z3, nullptr, 0);
    vecprep32<<<D / 256, 256, 0, stream>>>(z1, z2, z3, a1, a2, b3, out, s3, g2, g1);

    const size_t PLA = (size_t)16 * CTK * 8192;   // A1 / C / B2 plane (ushorts)
    const size_t PLB1 = (size_t)20 * CTK * 4096;  // B1 plane (ushorts)
    size_t o_scan = smallB;
    size_t o_A1 = o_scan + 65536;
    size_t o_B1 = o_A1 + 3 * PLA * 2;
    size_t o_C = o_B1 + 3 * PLB1 * 2;
    size_t newNeed = o_C + 3 * PLA * 2 + 256;

    const size_t PL = (size_t)D * D;
    size_t need1 = smallB + 3 * PL * 2 + (size_t)D * D * 4 + 256;

    if (ws_size >= newNeed) {
        int* idx2 = (int*)(ws + o_scan);
        float* g2c = (float*)(idx2 + CAP);
        int* idx1 = (int*)(g2c + CAP);
        float* g1c = (float*)(idx1 + CAP);
        int* cnt = (int*)(g1c + CAP);
        ushort* A1 = (ushort*)(ws + o_A1);
        ushort* B1 = (ushort*)(ws + o_B1);
        ushort* Cp = (ushort*)(ws + o_C);
        ushort* B2 = A1;  // aliases A1 (dead after gemm_c2<1>)

        scan2<<<1, 64, 0, stream>>>(g2, g1, idx2, g2c, idx1, g1c, cnt);
        prepA1c<<<(int)(16 * CTK * 1024 / 256), 256, 0, stream>>>(W3, s3, idx2, g2c,
                                                                  A1, A1 + PLA, A1 + 2 * PLA);
        prepB1c<<<(int)(20 * CTK * 512 / 256), 256, 0, stream>>>(W2, idx2, idx1,
                                                                 B1, B1 + PLB1, B1 + 2 * PLB1);
        dim3 g1d(CAP / 128, 16);
        gemm_c2<1><<<g1d, 512, 0, stream>>>(A1, A1 + PLA, A1 + 2 * PLA,
                                            B1, B1 + PLB1, B1 + 2 * PLB1,
                                            g1c, cnt, nullptr,
                                            Cp, Cp + PLA, Cp + 2 * PLA);
        prepB2c<<<32 * (CAP / 64), 256, 0, stream>>>(W1, idx1, B2, B2 + PLA, B2 + 2 * PLA);
        dim3 g2d(32, 16);
        gemm_c2<0><<<g2d, 512, 0, stream>>>(Cp, Cp + PLA, Cp + 2 * PLA,
                                            B2, B2 + PLA, B2 + 2 * PLA,
                                            x, cnt, Rout, nullptr, nullptr, nullptr);
    } else if (ws_size >= need1) {
        ushort* Bpl = (ushort*)(ws + smallB);
        float* C = (float*)(ws + smallB + 3 * PL * 2);
        dim3 gg(D / 128, D / 128);
        int pgrid = (D / 128) * (D / 64);
        prepBT<<<pgrid, 256, 0, stream>>>(W2, Bpl, Bpl + PL, Bpl + 2 * PL);
        gemm_bs<1><<<gg, 256, 0, stream>>>(W3, Bpl, Bpl + PL, Bpl + 2 * PL, s3, g2, g1, C);
        prepBT<<<pgrid, 256, 0, stream>>>(W1, Bpl, Bpl + PL, Bpl + 2 * PL);
        gemm_bs<0><<<gg, 256, 0, stream>>>(C, Bpl, Bpl + PL, Bpl + 2 * PL, nullptr, nullptr, x, Rout);
    }
}

// Round 23
// 665.447 us; speedup vs baseline: 1.0706x; 1.0706x over previous
//
#include <hip/hip_runtime.h>
#include <stdint.h>

#define D 4096
#define CAP 2560          // compacted-dim capacity (counts ~2048 +- ~45)
#define CTK 80            // CAP/32 k-tile stride

typedef __attribute__((ext_vector_type(8))) short bf16x8;
typedef __attribute__((ext_vector_type(4))) float f32x4;

#define MFMA16 __builtin_amdgcn_mfma_f32_16x16x32_bf16

__device__ __forceinline__ float sgnf(float z) {
    return (z > 0.f) ? 1.f : ((z < 0.f) ? -1.f : 0.f);
}
__device__ __forceinline__ uint cvtpk(float a, float b) {
    uint r;
    asm("v_cvt_pk_bf16_f32 %0, %1, %2" : "=v"(r) : "v"(a), "v"(b));
    return r;
}
__device__ __forceinline__ void split3_pk(float f0, float f1, uint& hp, uint& mp, uint& lp) {
    hp = cvtpk(f0, f1);
    float h0 = __uint_as_float(hp << 16);
    float h1 = __uint_as_float(hp & 0xffff0000u);
    float r0 = f0 - h0, r1 = f1 - h1;
    mp = cvtpk(r0, r1);
    float m0 = __uint_as_float(mp << 16);
    float m1 = __uint_as_float(mp & 0xffff0000u);
    lp = cvtpk(r0 - m0, r1 - m1);
}

// ---- forward GEMV: bit-exact numpy-f32 emulation (R19-proven, pipelined) ----
__global__ __launch_bounds__(256) void gemv_blas8(const float* __restrict__ W,
                                                  const float* __restrict__ v,
                                                  const float* __restrict__ bias,
                                                  float* __restrict__ z,
                                                  float* __restrict__ act, int doAct) {
    __shared__ float vs[D];
    {
        const float4* v4 = (const float4*)v;
        float4* s4 = (float4*)vs;
#pragma unroll
        for (int q = 0; q < 4; q++) s4[threadIdx.x + q * 256] = v4[threadIdx.x + q * 256];
    }
    __syncthreads();
    int gid = blockIdx.x * 256 + threadIdx.x;
    int row = gid >> 3;
    int l = gid & 7;
    const float* wr = W + (size_t)row * D + l;
    float wb0[16], wb1[16], wb2[16];
    float acc = 0.f;
#pragma unroll
    for (int u = 0; u < 16; u++) wb0[u] = wr[u * 8];
#pragma unroll
    for (int u = 0; u < 16; u++) wb1[u] = wr[(16 + u) * 8];
#pragma unroll
    for (int c = 0; c < 32; c++) {
        if (c + 2 < 32) {
            float* dst = ((c + 2) % 3 == 0) ? wb0 : ((c + 2) % 3 == 1) ? wb1 : wb2;
#pragma unroll
            for (int u = 0; u < 16; u++) dst[u] = wr[((c + 2) * 16 + u) * 8];
        }
        const float* cur = (c % 3 == 0) ? wb0 : (c % 3 == 1) ? wb1 : wb2;
#pragma unroll
        for (int u = 0; u < 16; u++) acc = fmaf(cur[u], vs[l + (c * 16 + u) * 8], acc);
    }
    float b = acc + __shfl_xor(acc, 4);
    float c2 = b + __shfl_xor(b, 1);
    float s = c2 + __shfl_xor(c2, 2);
    if (l == 0) {
        z[row] = s;
        if (doAct) act[row] = fmaxf(s + bias[row], 0.f);
    }
}

__global__ __launch_bounds__(256) void vecprep32(const float* __restrict__ z1,
                                                 const float* __restrict__ z2,
                                                 const float* __restrict__ z3,
                                                 const float* __restrict__ a1,
                                                 const float* __restrict__ a2,
                                                 const float* __restrict__ b3,
                                                 float* __restrict__ out,
                                                 float* __restrict__ s3,
                                                 float* __restrict__ g2,
                                                 float* __restrict__ g1) {
    int i = blockIdx.x * 256 + threadIdx.x;
    float z3v = z3[i];
    float o = z3v + b3[i];
    out[i] = o;
    s3[i] = o / (z3v + 1e-9f * sgnf(z3v));
    float z2v = z2[i];
    g2[i] = a2[i] / (z2v + 1e-9f * sgnf(z2v));
    float z1v = z1[i];
    g1[i] = a1[i] / (z1v + 1e-9f * sgnf(z1v));
}

// ---- compaction scan (1 wave, deterministic) ----
__global__ __launch_bounds__(64) void scan2(const float* __restrict__ g2,
                                            const float* __restrict__ g1,
                                            int* __restrict__ idx2, float* __restrict__ g2c,
                                            int* __restrict__ idx1, float* __restrict__ g1c,
                                            int* __restrict__ cnt) {
    int lane = threadIdx.x;
    unsigned long long lt = (lane == 63) ? 0x7fffffffffffffffULL : ((1ULL << lane) - 1ULL);
    int base = 0;
    for (int c = 0; c < 64; ++c) {
        float v = g2[c * 64 + lane];
        bool nz = (v != 0.f);
        unsigned long long mask = __ballot(nz);
        int pre = __popcll(mask & lt);
        if (nz && base + pre < CAP) { idx2[base + pre] = c * 64 + lane; g2c[base + pre] = v; }
        base += __popcll(mask);
    }
    if (base > CAP) base = CAP;
    for (int i = base + lane; i < CAP; i += 64) { idx2[i] = 0; g2c[i] = 0.f; }
    int K2pad = (base + 127) & ~127;
    int b1 = 0;
    for (int c = 0; c < 64; ++c) {
        float v = g1[c * 64 + lane];
        bool nz = (v != 0.f);
        unsigned long long mask = __ballot(nz);
        int pre = __popcll(mask & lt);
        if (nz && b1 + pre < CAP) { idx1[b1 + pre] = c * 64 + lane; g1c[b1 + pre] = v; }
        b1 += __popcll(mask);
    }
    if (b1 > CAP) b1 = CAP;
    for (int i = b1 + lane; i < CAP; i += 64) { idx1[i] = 0; g1c[i] = 0.f; }
    int N1pad = (b1 + 127) & ~127;
    if (lane == 0) {
        cnt[0] = K2pad / 32;
        cnt[1] = N1pad / 32;
        cnt[2] = N1pad;
        cnt[3] = K2pad;
    }
}

// ---- A1 planes: val = s3[i]*W3[i,idx2[kc]]*g2c[kc] (256-row-block layout) ----
__global__ __launch_bounds__(256) void prepA1c(const float* __restrict__ W3,
                                               const float* __restrict__ s3,
                                               const int* __restrict__ idx2,
                                               const float* __restrict__ g2c,
                                               ushort* __restrict__ Ph,
                                               ushort* __restrict__ Pm,
                                               ushort* __restrict__ Pl) {
    size_t ci = (size_t)blockIdx.x * 256 + threadIdx.x;
    int cell = (int)(ci & 1023);
    int kt = (int)((ci >> 10) % CTK);
    int bi2 = (int)(ci / (1024 * CTK));
    int mm = cell >> 6, gg = (cell >> 4) & 3, ri = cell & 15;
    int i = bi2 * 256 + mm * 16 + ri;
    int kc0 = kt * 32 + gg * 8;
    float s = s3[i];
    const float* w3r = W3 + (size_t)i * D;
    float v[8];
#pragma unroll
    for (int j = 0; j < 8; j++) v[j] = w3r[idx2[kc0 + j]] * (s * g2c[kc0 + j]);
    uint hp[4], mp[4], lp[4];
#pragma unroll
    for (int j = 0; j < 4; j++) split3_pk(v[2 * j], v[2 * j + 1], hp[j], mp[j], lp[j]);
    size_t dst = ci * 8;
    uint4 u;
    u.x = hp[0]; u.y = hp[1]; u.z = hp[2]; u.w = hp[3]; *(uint4*)(Ph + dst) = u;
    u.x = mp[0]; u.y = mp[1]; u.z = mp[2]; u.w = mp[3]; *(uint4*)(Pm + dst) = u;
    u.x = lp[0]; u.y = lp[1]; u.z = lp[2]; u.w = lp[3]; *(uint4*)(Pl + dst) = u;
}

// ---- B1 planes: val = W2[idx2[kc], idx1[colc]] (double-gather) ----
__global__ __launch_bounds__(256) void prepB1c(const float* __restrict__ W2,
                                               const int* __restrict__ idx2,
                                               const int* __restrict__ idx1,
                                               ushort* __restrict__ Ph,
                                               ushort* __restrict__ Pm,
                                               ushort* __restrict__ Pl) {
    size_t ci = (size_t)blockIdx.x * 256 + threadIdx.x;
    int cell = (int)(ci & 511);
    int kt = (int)((ci >> 9) % CTK);
    int bi = (int)(ci / (512 * CTK));
    int m = cell >> 6, g = (cell >> 4) & 3, r = cell & 15;
    int col = idx1[bi * 128 + m * 16 + r];
    int kc0 = kt * 32 + g * 8;
    float v[8];
#pragma unroll
    for (int j = 0; j < 8; j++) v[j] = W2[(size_t)idx2[kc0 + j] * D + col];
    uint hp[4], mp[4], lp[4];
#pragma unroll
    for (int j = 0; j < 4; j++) split3_pk(v[2 * j], v[2 * j + 1], hp[j], mp[j], lp[j]);
    size_t dst = ci * 8;
    uint4 u;
    u.x = hp[0]; u.y = hp[1]; u.z = hp[2]; u.w = hp[3]; *(uint4*)(Ph + dst) = u;
    u.x = mp[0]; u.y = mp[1]; u.z = mp[2]; u.w = mp[3]; *(uint4*)(Pm + dst) = u;
    u.x = lp[0]; u.y = lp[1]; u.z = lp[2]; u.w = lp[3]; *(uint4*)(Pl + dst) = u;
}

// ---- B2 planes: val = W1[idx1[kc], col] (row-gather, LDS-tiled) ----
__global__ __launch_bounds__(256) void prepB2c(const float* __restrict__ W1,
                                               const int* __restrict__ idx1,
                                               ushort* __restrict__ Ph,
                                               ushort* __restrict__ Pm,
                                               ushort* __restrict__ Pl) {
    __shared__ float tile[64][129];
    int bi = blockIdx.x / (CAP / 64);
    int kch = blockIdx.x % (CAP / 64);
    int k0 = kch * 64;
    int c0 = bi * 128;
    int t = threadIdx.x;
#pragma unroll
    for (int q = 0; q < 8; q++) {
        int idx = t + q * 256;
        int rr = idx >> 5;
        int c4 = idx & 31;
        int row = idx1[k0 + rr];
        float4 wv = *(const float4*)(W1 + (size_t)row * D + c0 + c4 * 4);
        tile[rr][c4 * 4 + 0] = wv.x;
        tile[rr][c4 * 4 + 1] = wv.y;
        tile[rr][c4 * 4 + 2] = wv.z;
        tile[rr][c4 * 4 + 3] = wv.w;
    }
    __syncthreads();
#pragma unroll
    for (int q = 0; q < 4; q++) {
        int oi = t + q * 256;
        int ktl = oi >> 9;
        int rem = oi & 511;
        int m = rem >> 6, g = (rem >> 4) & 3, r = rem & 15;
        int col = m * 16 + r;
        float vv[8];
#pragma unroll
        for (int j = 0; j < 8; j++) vv[j] = tile[ktl * 32 + g * 8 + j][col];
        uint hp[4], mp[4], lp[4];
#pragma unroll
        for (int j = 0; j < 4; j++) split3_pk(vv[2 * j], vv[2 * j + 1], hp[j], mp[j], lp[j]);
        size_t dst = (((size_t)bi * CTK + kch * 2 + ktl) * 512 + rem) * 8;
        uint4 u;
        u.x = hp[0]; u.y = hp[1]; u.z = hp[2]; u.w = hp[3]; *(uint4*)(Ph + dst) = u;
        u.x = mp[0]; u.y = mp[1]; u.z = mp[2]; u.w = mp[3]; *(uint4*)(Pm + dst) = u;
        u.x = lp[0]; u.y = lp[1]; u.z = lp[2]; u.w = lp[3]; *(uint4*)(Pl + dst) = u;
    }
}

// ---- gemm_c: all-DMA, SINGLE-buffered A and B (48 KB LDS -> 3 blocks/CU).
// Per tile: MFMA -> barrier -> DMA(A,B of t+1) -> vmcnt(0) -> barrier.
// Drain stall covered by the 2 sibling blocks' MFMA phases (m114 overlap).
template <int MODE>
__global__ __launch_bounds__(256, 3) void gemm_c(const ushort* __restrict__ Ah,
                                                 const ushort* __restrict__ Am_,
                                                 const ushort* __restrict__ Al_,
                                                 const ushort* __restrict__ Bh,
                                                 const ushort* __restrict__ Bm_,
                                                 const ushort* __restrict__ Bl_,
                                                 const float* __restrict__ cs,
                                                 const int* __restrict__ cnt,
                                                 float* __restrict__ O,
                                                 ushort* __restrict__ Cph,
                                                 ushort* __restrict__ Cpm,
                                                 ushort* __restrict__ Cpl_) {
    const int NT = cnt[MODE == 1 ? 0 : 1];
    if (MODE == 1 && (int)blockIdx.x * 128 >= cnt[2]) return;
    __shared__ ushort ldsA[3][4096];  // 24 KB, single
    __shared__ ushort ldsB[3][4096];  // 24 KB, single
    int t = threadIdx.x;
    int lane = t & 63, wv = t >> 6;
    int wr = wv >> 1, wc = wv & 1;
    int r = lane & 15, g = lane >> 4;
    int bx = blockIdx.x, by = blockIdx.y;
    size_t row0 = (size_t)by * 128, col0 = (size_t)bx * 128;

    f32x4 acc[4][4];
#pragma unroll
    for (int m = 0; m < 4; m++)
#pragma unroll
        for (int n = 0; n < 4; n++) acc[m][n] = (f32x4){0.f, 0.f, 0.f, 0.f};

    size_t abase = ((size_t)(by >> 1) * CTK) * 8192 + (size_t)(by & 1) * 4096;

    auto DMAA = [&](int kt) {
        size_t at = abase + (size_t)kt * 8192;
        const ushort* asrc[3] = {Ah + at, Am_ + at, Al_ + at};
#pragma unroll
        for (int p = 0; p < 3; p++) {
            __builtin_amdgcn_global_load_lds(
                (const __attribute__((address_space(1))) uint32_t*)(asrc[p] + (size_t)t * 8),
                (__attribute__((address_space(3))) uint32_t*)(&ldsA[p][t * 8]), 16, 0, 0);
            __builtin_amdgcn_global_load_lds(
                (const __attribute__((address_space(1))) uint32_t*)(asrc[p] + (size_t)(t + 256) * 8),
                (__attribute__((address_space(3))) uint32_t*)(&ldsA[p][(t + 256) * 8]), 16, 0, 0);
        }
    };
    auto DMAB = [&](int kt) {
        size_t bt = ((size_t)bx * CTK + kt) * 4096;
        const ushort* bsrc[3] = {Bh + bt, Bm_ + bt, Bl_ + bt};
#pragma unroll
        for (int p = 0; p < 3; p++) {
            __builtin_amdgcn_global_load_lds(
                (const __attribute__((address_space(1))) uint32_t*)(bsrc[p] + (size_t)t * 8),
                (__attribute__((address_space(3))) uint32_t*)(&ldsB[p][t * 8]), 16, 0, 0);
            __builtin_amdgcn_global_load_lds(
                (const __attribute__((address_space(1))) uint32_t*)(bsrc[p] + (size_t)(t + 256) * 8),
                (__attribute__((address_space(3))) uint32_t*)(&ldsB[p][(t + 256) * 8]), 16, 0, 0);
        }
    };

    auto MFMA_PHASE = [&]() {
        __builtin_amdgcn_s_setprio(1);
        bf16x8 bh[4], bm[4], bl[4];
#pragma unroll
        for (int n = 0; n < 4; n++) bh[n] = *(const bf16x8*)&ldsB[0][(wc * 4 + n) * 512 + lane * 8];
#pragma unroll
        for (int n = 0; n < 4; n++) bm[n] = *(const bf16x8*)&ldsB[1][(wc * 4 + n) * 512 + lane * 8];
#pragma unroll
        for (int n = 0; n < 4; n++) bl[n] = *(const bf16x8*)&ldsB[2][(wc * 4 + n) * 512 + lane * 8];
        {
            bf16x8 a[4];
#pragma unroll
            for (int m = 0; m < 4; m++) a[m] = *(const bf16x8*)&ldsA[0][(wr * 4 + m) * 512 + lane * 8];
#pragma unroll
            for (int m = 0; m < 4; m++)
#pragma unroll
                for (int n = 0; n < 4; n++) {
                    acc[m][n] = MFMA16(a[m], bh[n], acc[m][n], 0, 0, 0);
                    acc[m][n] = MFMA16(a[m], bm[n], acc[m][n], 0, 0, 0);
                    acc[m][n] = MFMA16(a[m], bl[n], acc[m][n], 0, 0, 0);
                }
        }
        {
            bf16x8 a[4];
#pragma unroll
            for (int m = 0; m < 4; m++) a[m] = *(const bf16x8*)&ldsA[1][(wr * 4 + m) * 512 + lane * 8];
#pragma unroll
            for (int m = 0; m < 4; m++)
#pragma unroll
                for (int n = 0; n < 4; n++) {
                    acc[m][n] = MFMA16(a[m], bh[n], acc[m][n], 0, 0, 0);
                    acc[m][n] = MFMA16(a[m], bm[n], acc[m][n], 0, 0, 0);
                }
        }
        {
            bf16x8 a[4];
#pragma unroll
            for (int m = 0; m < 4; m++) a[m] = *(const bf16x8*)&ldsA[2][(wr * 4 + m) * 512 + lane * 8];
#pragma unroll
            for (int m = 0; m < 4; m++)
#pragma unroll
                for (int n = 0; n < 4; n++)
                    acc[m][n] = MFMA16(a[m], bh[n], acc[m][n], 0, 0, 0);
        }
        __builtin_amdgcn_s_setprio(0);
    };

    DMAA(0);
    DMAB(0);
    asm volatile("s_waitcnt vmcnt(0)" ::: "memory");
    __builtin_amdgcn_sched_barrier(0);
    __builtin_amdgcn_s_barrier();
    __builtin_amdgcn_sched_barrier(0);

    for (int tt = 0; tt < NT; ++tt) {
        MFMA_PHASE();
        __builtin_amdgcn_sched_barrier(0);
        __builtin_amdgcn_s_barrier();  // all waves done reading ldsA/ldsB
        __builtin_amdgcn_sched_barrier(0);
        if (tt < NT - 1) {
            DMAA(tt + 1);
            DMAB(tt + 1);
            asm volatile("s_waitcnt vmcnt(0)" ::: "memory");
            __builtin_amdgcn_sched_barrier(0);
            __builtin_amdgcn_s_barrier();
            __builtin_amdgcn_sched_barrier(0);
        }
    }

    float csv[4];
#pragma unroll
    for (int n = 0; n < 4; n++) csv[n] = cs[col0 + wc * 64 + n * 16 + r];
#pragma unroll
    for (int m = 0; m < 4; m++)
#pragma unroll
        for (int n = 0; n < 4; n++) {
            if (MODE == 0) {
#pragma unroll
                for (int j = 0; j < 4; j++) {
                    size_t grow = row0 + wr * 64 + m * 16 + g * 4 + j;
                    size_t gcol = col0 + wc * 64 + n * 16 + r;
                    O[grow * D + gcol] = acc[m][n][j] * csv[n];
                }
            } else {
                float v0 = acc[m][n][0] * csv[n], v1 = acc[m][n][1] * csv[n];
                float v2 = acc[m][n][2] * csv[n], v3 = acc[m][n][3] * csv[n];
                uint hp0, mp0, lp0, hp1, mp1, lp1;
                split3_pk(v0, v1, hp0, mp0, lp0);
                split3_pk(v2, v3, hp1, mp1, lp1);
                int k = (int)(col0 + wc * 64 + n * 16 + r);  // compact col = GEMM2 k
                int ktc = k >> 5, gg = (k & 31) >> 3, jj = k & 7;
#pragma unroll
                for (int j = 0; j < 4; j++) {
                    int i = (int)(row0 + wr * 64 + m * 16 + g * 4 + j);
                    int bi = i >> 8, mm = (i & 255) >> 4, ri = i & 15;
                    size_t off = ((size_t)bi * CTK + ktc) * 8192 +
                                 (size_t)(mm * 64 + gg * 16 + ri) * 8 + jj;
                    uint hpk = (j < 2) ? hp0 : hp1;
                    uint mpk = (j < 2) ? mp0 : mp1;
                    uint lpk = (j < 2) ? lp0 : lp1;
                    int sh = (j & 1) * 16;
                    Cph[off] = (ushort)(hpk >> sh);
                    Cpm[off] = (ushort)(mpk >> sh);
                    Cpl_[off] = (ushort)(lpk >> sh);
                }
            }
        }
}

// ================= fallback tier kernels (R19-proven) =================
__global__ __launch_bounds__(256) void prepBT(const float* __restrict__ W,
                                              ushort* __restrict__ Ph,
                                              ushort* __restrict__ Pm,
                                              ushort* __restrict__ Pl) {
    __shared__ float tile[64][129];
    int bi = blockIdx.x >> 6;
    int kpair = blockIdx.x & 63;
    int k0 = kpair * 64;
    int c0 = bi * 128;
    int t = threadIdx.x;
#pragma unroll
    for (int q = 0; q < 8; q++) {
        int idx = t + q * 256;
        int rr = idx >> 5;
        int c4 = idx & 31;
        float4 wv = *(const float4*)(W + (size_t)(k0 + rr) * D + c0 + c4 * 4);
        tile[rr][c4 * 4 + 0] = wv.x;
        tile[rr][c4 * 4 + 1] = wv.y;
        tile[rr][c4 * 4 + 2] = wv.z;
        tile[rr][c4 * 4 + 3] = wv.w;
    }
    __syncthreads();
#pragma unroll
    for (int q = 0; q < 4; q++) {
        int oi = t + q * 256;
        int ktl = oi >> 9;
        int rem = oi & 511;
        int m = rem >> 6, g = (rem >> 4) & 3, r = rem & 15;
        int col = m * 16 + r;
        float vv[8];
#pragma unroll
        for (int j = 0; j < 8; j++) vv[j] = tile[ktl * 32 + g * 8 + j][col];
        uint hp[4], mp[4], lp[4];
#pragma unroll
        for (int j = 0; j < 4; j++) split3_pk(vv[2 * j], vv[2 * j + 1], hp[j], mp[j], lp[j]);
        size_t dst = (((size_t)bi * 128 + kpair * 2 + ktl) * 512 + rem) * 8;
        uint4 u;
        u.x = hp[0]; u.y = hp[1]; u.z = hp[2]; u.w = hp[3]; *(uint4*)(Ph + dst) = u;
        u.x = mp[0]; u.y = mp[1]; u.z = mp[2]; u.w = mp[3]; *(uint4*)(Pm + dst) = u;
        u.x = lp[0]; u.y = lp[1]; u.z = lp[2]; u.w = lp[3]; *(uint4*)(Pl + dst) = u;
    }
}

template <int SCALED>
__global__ __launch_bounds__(256, 2) void gemm_bs(const float* __restrict__ A,
                                                  const ushort* __restrict__ Bh,
                                                  const ushort* __restrict__ Bm_,
                                                  const ushort* __restrict__ Bl_,
                                                  const float* __restrict__ rs,
                                                  const float* __restrict__ ks,
                                                  const float* __restrict__ cs,
                                                  float* __restrict__ O) {
    __shared__ ushort ldsA[3][4096];
    __shared__ ushort ldsB[2][3][4096];
    int t = threadIdx.x;
    int lane = t & 63, wv = t >> 6;
    int wr = wv >> 1, wc = wv & 1;
    int r = lane & 15, g = lane >> 4;
    int bx = blockIdx.x, by = blockIdx.y;
    size_t row0 = (size_t)by * 128, col0 = (size_t)bx * 128;
    int rr = t >> 1;
    int kh = t & 1;
    int cellb0 = ((rr >> 4) * 64 + (kh * 2 + 0) * 16 + (rr & 15)) * 8;
    int cellb1 = ((rr >> 4) * 64 + (kh * 2 + 1) * 16 + (rr & 15)) * 8;
    f32x4 acc[4][4];
#pragma unroll
    for (int m = 0; m < 4; m++)
#pragma unroll
        for (int n = 0; n < 4; n++) acc[m][n] = (f32x4){0.f, 0.f, 0.f, 0.f};
    float rsv = SCALED ? rs[row0 + rr] : 0.f;
    const float* arow = A + (row0 + rr) * (size_t)D;
    float av[16];
    auto LOADA = [&](int k0) {
        const float4* pa = (const float4*)(arow + k0 + kh * 16);
#pragma unroll
        for (int qq = 0; qq < 4; qq++) {
            float4 w = pa[qq];
            av[qq * 4 + 0] = w.x; av[qq * 4 + 1] = w.y;
            av[qq * 4 + 2] = w.z; av[qq * 4 + 3] = w.w;
        }
        if (SCALED) {
            const float4* pk = (const float4*)(ks + k0 + kh * 16);
#pragma unroll
            for (int qq = 0; qq < 4; qq++) {
                float4 kk = pk[qq];
                av[qq * 4 + 0] *= rsv * kk.x; av[qq * 4 + 1] *= rsv * kk.y;
                av[qq * 4 + 2] *= rsv * kk.z; av[qq * 4 + 3] *= rsv * kk.w;
            }
        }
    };
    auto DMAB = [&](int kt, int buf) {
        size_t bt = ((size_t)bx * 128 + kt) * 4096;
        const ushort* bsrc[3] = {Bh + bt, Bm_ + bt, Bl_ + bt};
#pragma unroll
        for (int p = 0; p < 3; p++) {
            __builtin_amdgcn_global_load_lds(
                (const __attribute__((address_space(1))) uint32_t*)(bsrc[p] + (size_t)t * 8),
                (__attribute__((address_space(3))) uint32_t*)(&ldsB[buf][p][t * 8]), 16, 0, 0);
            __builtin_amdgcn_global_load_lds(
                (const __attribute__((address_space(1))) uint32_t*)(bsrc[p] + (size_t)(t + 256) * 8),
                (__attribute__((address_space(3))) uint32_t*)(&ldsB[buf][p][(t + 256) * 8]), 16, 0, 0);
        }
    };
    auto SPLITA = [&]() {
        uint hp[8], mp[8], lp[8];
#pragma unroll
        for (int j = 0; j < 8; j++) split3_pk(av[2 * j], av[2 * j + 1], hp[j], mp[j], lp[j]);
        uint4 u;
        u.x = hp[0]; u.y = hp[1]; u.z = hp[2]; u.w = hp[3]; *(uint4*)&ldsA[0][cellb0] = u;
        u.x = hp[4]; u.y = hp[5]; u.z = hp[6]; u.w = hp[7]; *(uint4*)&ldsA[0][cellb1] = u;
        u.x = mp[0]; u.y = mp[1]; u.z = mp[2]; u.w = mp[3]; *(uint4*)&ldsA[1][cellb0] = u;
        u.x = mp[4]; u.y = mp[5]; u.z = mp[6]; u.w = mp[7]; *(uint4*)&ldsA[1][cellb1] = u;
        u.x = lp[0]; u.y = lp[1]; u.z = lp[2]; u.w = lp[3]; *(uint4*)&ldsA[2][cellb0] = u;
        u.x = lp[4]; u.y = lp[5]; u.z = lp[6]; u.w = lp[7]; *(uint4*)&ldsA[2][cellb1] = u;
    };
    auto MFMA_PHASE = [&](int buf) {
        bf16x8 bh[4], bm[4], bl[4];
#pragma unroll
        for (int n = 0; n < 4; n++) bh[n] = *(const bf16x8*)&ldsB[buf][0][(wc * 4 + n) * 512 + lane * 8];
#pragma unroll
        for (int n = 0; n < 4; n++) bm[n] = *(const bf16x8*)&ldsB[buf][1][(wc * 4 + n) * 512 + lane * 8];
#pragma unroll
        for (int n = 0; n < 4; n++) bl[n] = *(const bf16x8*)&ldsB[buf][2][(wc * 4 + n) * 512 + lane * 8];
        {
            bf16x8 a[4];
#pragma unroll
            for (int m = 0; m < 4; m++) a[m] = *(const bf16x8*)&ldsA[0][(wr * 4 + m) * 512 + lane * 8];
#pragma unroll
            for (int m = 0; m < 4; m++)
#pragma unroll
                for (int n = 0; n < 4; n++) {
                    acc[m][n] = MFMA16(a[m], bh[n], acc[m][n], 0, 0, 0);
                    acc[m][n] = MFMA16(a[m], bm[n], acc[m][n], 0, 0, 0);
                    acc[m][n] = MFMA16(a[m], bl[n], acc[m][n], 0, 0, 0);
                }
        }
        {
            bf16x8 a[4];
#pragma unroll
            for (int m = 0; m < 4; m++) a[m] = *(const bf16x8*)&ldsA[1][(wr * 4 + m) * 512 + lane * 8];
#pragma unroll
            for (int m = 0; m < 4; m++)
#pragma unroll
                for (int n = 0; n < 4; n++) {
                    acc[m][n] = MFMA16(a[m], bh[n], acc[m][n], 0, 0, 0);
                    acc[m][n] = MFMA16(a[m], bm[n], acc[m][n], 0, 0, 0);
                }
        }
        {
            bf16x8 a[4];
#pragma unroll
            for (int m = 0; m < 4; m++) a[m] = *(const bf16x8*)&ldsA[2][(wr * 4 + m) * 512 + lane * 8];
#pragma unroll
            for (int m = 0; m < 4; m++)
#pragma unroll
                for (int n = 0; n < 4; n++)
                    acc[m][n] = MFMA16(a[m], bh[n], acc[m][n], 0, 0, 0);
        }
    };
    const int NT = D / 32;
    LOADA(0);
    SPLITA();
    DMAB(0, 0);
    LOADA(32);
    DMAB(1, 1);
    asm volatile("s_waitcnt vmcnt(6) lgkmcnt(0)" ::: "memory");
    __builtin_amdgcn_s_barrier();
    __builtin_amdgcn_sched_barrier(0);
    for (int tt = 0; tt < NT; ++tt) {
        MFMA_PHASE(tt & 1);
        __builtin_amdgcn_sched_barrier(0);
        __builtin_amdgcn_s_barrier();
        __builtin_amdgcn_sched_barrier(0);
        if (tt < NT - 1) {
            SPLITA();
            if (tt < NT - 2) {
                LOADA((tt + 2) * 32);
                DMAB(tt + 2, tt & 1);
                asm volatile("s_waitcnt vmcnt(6) lgkmcnt(0)" ::: "memory");
            } else {
                asm volatile("s_waitcnt vmcnt(0) lgkmcnt(0)" ::: "memory");
            }
            __builtin_amdgcn_s_barrier();
            __builtin_amdgcn_sched_barrier(0);
        }
    }
    float csv[4];
#pragma unroll
    for (int n = 0; n < 4; n++) csv[n] = cs[col0 + wc * 64 + n * 16 + r];
#pragma unroll
    for (int m = 0; m < 4; m++)
#pragma unroll
        for (int n = 0; n < 4; n++)
#pragma unroll
            for (int j = 0; j < 4; j++) {
                size_t grow = row0 + wr * 64 + m * 16 + g * 4 + j;
                size_t gcol = col0 + wc * 64 + n * 16 + r;
                O[grow * D + gcol] = acc[m][n][j] * csv[n];
            }
}

extern "C" void kernel_launch(void* const* d_in, const int* in_sizes, int n_in,
                              void* d_out, int out_size, void* d_ws, size_t ws_size,
                              hipStream_t stream) {
    const float* x = (const float*)d_in[0];
    const float* W1 = (const float*)d_in[1];
    const float* b1 = (const float*)d_in[2];
    const float* W2 = (const float*)d_in[3];
    const float* b2 = (const float*)d_in[4];
    const float* W3 = (const float*)d_in[5];
    const float* b3 = (const float*)d_in[6];

    float* out = (float*)d_out;
    float* Rout = out + D;

    char* ws = (char*)d_ws;
    float* z1 = (float*)ws;
    float* z2 = z1 + D;
    float* z3 = z2 + D;
    float* a1 = z3 + D;
    float* a2 = a1 + D;
    float* s3 = a2 + D;
    float* g2 = s3 + D;
    float* g1 = g2 + D;
    size_t smallB = (size_t)D * 8 * sizeof(float);

    // forward pass (bit-exact numpy-f32 emulation)
    gemv_blas8<<<(D * 8) / 256, 256, 0, stream>>>(W1, x, b1, z1, a1, 1);
    gemv_blas8<<<(D * 8) / 256, 256, 0, stream>>>(W2, a1, b2, z2, a2, 1);
    gemv_blas8<<<(D * 8) / 256, 256, 0, stream>>>(W3, a2, b3, z3, nullptr, 0);
    vecprep32<<<D / 256, 256, 0, stream>>>(z1, z2, z3, a1, a2, b3, out, s3, g2, g1);

    const size_t PLA = (size_t)16 * CTK * 8192;   // A1 / C / B2 plane (ushorts)
    const size_t PLB1 = (size_t)20 * CTK * 4096;  // B1 plane (ushorts)
    size_t o_scan = smallB;
    size_t o_A1 = o_scan + 65536;
    size_t o_B1 = o_A1 + 3 * PLA * 2;
    size_t o_C = o_B1 + 3 * PLB1 * 2;
    size_t newNeed = o_C + 3 * PLA * 2 + 256;

    const size_t PL = (size_t)D * D;
    size_t need1 = smallB + 3 * PL * 2 + (size_t)D * D * 4 + 256;

    if (ws_size >= newNeed) {
        int* idx2 = (int*)(ws + o_scan);
        float* g2c = (float*)(idx2 + CAP);
        int* idx1 = (int*)(g2c + CAP);
        float* g1c = (float*)(idx1 + CAP);
        int* cnt = (int*)(g1c + CAP);
        ushort* A1 = (ushort*)(ws + o_A1);
        ushort* B1 = (ushort*)(ws + o_B1);
        ushort* Cp = (ushort*)(ws + o_C);
        ushort* B2 = A1;  // aliases A1 (dead after gemm_c<1>)

        scan2<<<1, 64, 0, stream>>>(g2, g1, idx2, g2c, idx1, g1c, cnt);
        prepA1c<<<(int)(16 * CTK * 1024 / 256), 256, 0, stream>>>(W3, s3, idx2, g2c,
                                                                  A1, A1 + PLA, A1 + 2 * PLA);
        prepB1c<<<(int)(20 * CTK * 512 / 256), 256, 0, stream>>>(W2, idx2, idx1,
                                                                 B1, B1 + PLB1, B1 + 2 * PLB1);
        dim3 g1d(CAP / 128, 32);
        gemm_c<1><<<g1d, 256, 0, stream>>>(A1, A1 + PLA, A1 + 2 * PLA,
                                           B1, B1 + PLB1, B1 + 2 * PLB1,
                                           g1c, cnt, nullptr,
                                           Cp, Cp + PLA, Cp + 2 * PLA);
        prepB2c<<<32 * (CAP / 64), 256, 0, stream>>>(W1, idx1, B2, B2 + PLA, B2 + 2 * PLA);
        dim3 g2d(32, 32);
        gemm_c<0><<<g2d, 256, 0, stream>>>(Cp, Cp + PLA, Cp + 2 * PLA,
                                           B2, B2 + PLA, B2 + 2 * PLA,
                                           x, cnt, Rout, nullptr, nullptr, nullptr);
    } else if (ws_size >= need1) {
        ushort* Bpl = (ushort*)(ws + smallB);
        float* C = (float*)(ws + smallB + 3 * PL * 2);
        dim3 gg(D / 128, D / 128);
        int pgrid = (D / 128) * (D / 64);
        prepBT<<<pgrid, 256, 0, stream>>>(W2, Bpl, Bpl + PL, Bpl + 2 * PL);
        gemm_bs<1><<<gg, 256, 0, stream>>>(W3, Bpl, Bpl + PL, Bpl + 2 * PL, s3, g2, g1, C);
        prepBT<<<pgrid, 256, 0, stream>>>(W1, Bpl, Bpl + PL, Bpl + 2 * PL);
        gemm_bs<0><<<gg, 256, 0, stream>>>(C, Bpl, Bpl + PL, Bpl + 2 * PL, nullptr, nullptr, x, Rout);
    }
}